// Round 7
// baseline (473.204 us; speedup 1.0000x reference)
//
#include <hip/hip_runtime.h>
#include <hip/hip_bf16.h>

// Problem constants (fixed by setup_inputs)
#define NB 16     // batch
#define CC 64     // channels
#define TT 64
#define VV 25
#define LL 1600   // T*V
#define HH 4
#define DD 64
#define NH 64     // N*H

// Dtype contract (established rounds 0-3): d_in fp32, d_out fp32,
// tolerance bf16-grade (2% * max|ref|) -> internal bf16 pipeline OK.

typedef __hip_bfloat16 bf16;
typedef __attribute__((ext_vector_type(8))) short short8;
typedef __attribute__((ext_vector_type(4))) float f32x4;
typedef __attribute__((ext_vector_type(4))) unsigned short us4;

__device__ __forceinline__ float b2f(bf16 v) { return __bfloat162float(v); }
__device__ __forceinline__ unsigned short f2bf_bits(float f) {
  bf16 h = __float2bfloat16(f);
  return *(unsigned short*)&h;
}

// ---------------------------------------------------------------------------
// K0: weight prep. Wo[co][ci=256][r=9] fp32 -> Wt fragment-major bf16:
//   Wt[(((r*8+kc)*4+cot)*64+lane)*8+j] = Wo[cot*16+(lane&15)][kc*32+(lane>>4)*8+j][r]
// Wf[co][ci=64] fp32 -> WfT[(((kc*4)+cot)*64+lane)*8+j], kc in {0,1}.
// grid 576, block 256.
// ---------------------------------------------------------------------------
__global__ void k_prep(const float* __restrict__ Wo, const float* __restrict__ Wf,
                       bf16* __restrict__ Wt, bf16* __restrict__ WfT) {
  int i = blockIdx.x * 256 + threadIdx.x;
  if (i < 147456) {
    int j = i & 7, lane = (i >> 3) & 63, cot = (i >> 9) & 3;
    int kc = (i >> 11) & 7, r = i >> 14;
    int co = cot * 16 + (lane & 15);
    int ci = kc * 32 + (lane >> 4) * 8 + j;
    Wt[i] = __float2bfloat16(Wo[(co * 256 + ci) * 9 + r]);
  }
  if (i < 4096) {
    int j = i & 7, lane = (i >> 3) & 63, cot = (i >> 9) & 3, kc = (i >> 11) & 1;
    int co = cot * 16 + (lane & 15);
    int ci = kc * 32 + (lane >> 4) * 8 + j;
    WfT[i] = __float2bfloat16(Wf[co * 64 + ci]);
  }
}

// ---------------------------------------------------------------------------
// K1: qkv projection. x[N,C,T,V] (fp32) -> q,k [NH,L,D], vt [NH,D,L] (bf16).
// q pre-scaled by 0.125*log2(e) so attention softmax runs in base-2.
// grid 3200 = N * (L/8), block 256.
// ---------------------------------------------------------------------------
__global__ void k_qkv(const float* __restrict__ x, const float* __restrict__ Wq,
                      const float* __restrict__ bq,
                      bf16* __restrict__ q, bf16* __restrict__ k,
                      bf16* __restrict__ vt) {
  __shared__ float xr[64 * 8];  // [c][ll]
  int n = blockIdx.x / 200;
  int l0 = (blockIdx.x % 200) * 8;
  int tid = threadIdx.x;
  for (int idx = tid; idx < 512; idx += 256) {
    int c = idx >> 3, ll = idx & 7;
    xr[idx] = x[(size_t)(n * 64 + c) * 1600 + l0 + ll];
  }
  __syncthreads();
  int j0 = tid;  // 0..255
  float acc[3][8];
#pragma unroll
  for (int s = 0; s < 3; s++) {
    float bv = bq[s * 256 + j0];
#pragma unroll
    for (int ll = 0; ll < 8; ll++) acc[s][ll] = bv;
  }
  for (int c = 0; c < 64; c++) {
    float w0 = Wq[c * 768 + j0];
    float w1 = Wq[c * 768 + 256 + j0];
    float w2 = Wq[c * 768 + 512 + j0];
    const float* xc = &xr[c * 8];
#pragma unroll
    for (int ll = 0; ll < 8; ll++) {
      float xv = xc[ll];
      acc[0][ll] += xv * w0;
      acc[1][ll] += xv * w1;
      acc[2][ll] += xv * w2;
    }
  }
  int h = j0 >> 6, d = j0 & 63;
  const float QSCALE = 0.125f * 1.44269504f;  // 1/sqrt(64) * log2(e)
#pragma unroll
  for (int ll = 0; ll < 8; ll++) {
    size_t off = ((size_t)(n * 4 + h) * 1600 + (l0 + ll)) * 64 + d;
    q[off] = __float2bfloat16(acc[0][ll] * QSCALE);
    k[off] = __float2bfloat16(acc[1][ll]);
  }
  // vt[nh][d][l]: 8 contiguous l -> one 16B store
  unsigned short vb[8];
#pragma unroll
  for (int ll = 0; ll < 8; ll++) vb[ll] = f2bf_bits(acc[2][ll]);
  *(short8*)((short*)vt + ((size_t)(n * 4 + h) * 64 + d) * 1600 + l0) =
      *(short8*)vb;
}

// ---------------------------------------------------------------------------
// K2: MFMA flash attention, fixed-max softmax (p = exp2(s-8); uniform scale
// cancels in o = sum(p*v)/sum(p)).
// Round-7 structure: 256-thr blocks = 4 independent waves (one 16-row Q-tile
// each, same (n,h) -> shared K/V stream in L2), grid (25,64). K-fragments for
// kt+1 are manually prefetched BEFORE the LDS-transpose clobbers of kt
// (clobbers stop instruction motion, not waits -> issue-early, wait-late).
// launch_bounds(256,4): <=128 VGPR, ~4 blocks/CU.
// ---------------------------------------------------------------------------
__global__ __launch_bounds__(256, 4)
void k_attn(const bf16* __restrict__ q, const bf16* __restrict__ k,
            const bf16* __restrict__ vt, bf16* __restrict__ ot) {
  __shared__ short pl_all[4][1152];  // per-wave: P [16 m][72 j] / epi [16 l][66 d]
  int tid = threadIdx.x;
  int wv = tid >> 6, lane = tid & 63;
  short* pl = pl_all[wv];
  int bx = blockIdx.x * 4 + wv;   // Q-row tile (16 rows), 0..99
  int nh = blockIdx.y;            // 0..63
  int quad = lane >> 4, c = lane & 15;

  const short* qb = (const short*)q + ((size_t)nh * 1600 + bx * 16 + c) * 64 + quad * 8;
  short8 qf0 = *(const short8*)(qb);
  short8 qf1 = *(const short8*)(qb + 32);

  short ob = (c == 0) ? (short)0x3F80 : (short)0;  // bf16 1.0 in col 0
  short8 onesf = {ob, ob, ob, ob, ob, ob, ob, ob};

  f32x4 acc_o[5] = {};                 // 4 d-tiles + l-tile (ones-trick)

  const short* kbase = (const short*)k + (size_t)nh * 102400 + quad * 8;
  const short* vbase = (const short*)vt + (size_t)nh * 102400 + quad * 8;
  bool ev = (c & 1) == 0;
  int cbase = c & ~1;

  // --- prologue: K fragments for kt=0 ---
  short8 kf[4][2];
#pragma unroll
  for (int ct = 0; ct < 4; ct++) {
    const short* p0 = kbase + (size_t)(ct * 16 + c) * 64;
    kf[ct][0] = *(const short8*)(p0);
    kf[ct][1] = *(const short8*)(p0 + 32);
  }

  for (int kt = 0; kt < 25; kt++) {
    // --- scores (base-2 domain; Q pre-scaled) using prefetched kf ---
    f32x4 s[4];
#pragma unroll
    for (int ct = 0; ct < 4; ct++) {
      f32x4 z = {0.f, 0.f, 0.f, 0.f};
      z = __builtin_amdgcn_mfma_f32_16x16x32_bf16(qf0, kf[ct][0], z, 0, 0, 0);
      z = __builtin_amdgcn_mfma_f32_16x16x32_bf16(qf1, kf[ct][1], z, 0, 0, 0);
      s[ct] = z;
    }
    // --- V fragments for kt: issued now, drain under exp2/pack/LDS ---
    short8 vf[4][2];
#pragma unroll
    for (int ct = 0; ct < 4; ct++) {
      const short* p0 = vbase + (size_t)(ct * 16 + c) * 1600 + kt * 64;
      vf[ct][0] = *(const short8*)(p0);
      vf[ct][1] = *(const short8*)(p0 + 32);
    }
    // --- K fragments for kt+1: prefetch BEFORE the clobber section so the
    //     next iteration's QK^T never sees exposed global latency ---
    if (kt < 24) {
#pragma unroll
      for (int ct = 0; ct < 4; ct++) {
        const short* p0 = kbase + (size_t)((kt + 1) * 64 + ct * 16 + c) * 64;
        kf[ct][0] = *(const short8*)(p0);
        kf[ct][1] = *(const short8*)(p0 + 32);
      }
    }
    // --- p = exp2(s - 8); C-layout -> A-layout LDS (wave-private) ---
#pragma unroll
    for (int ct = 0; ct < 4; ct++)
#pragma unroll
      for (int r = 0; r < 4; r++) s[ct][r] = exp2f(s[ct][r] - 8.0f);
    asm volatile("" ::: "memory");
#pragma unroll
    for (int ct = 0; ct < 4; ct++) {
      float x0 = __shfl_xor(s[ct][0], 1);
      float x1 = __shfl_xor(s[ct][1], 1);
      float x2 = __shfl_xor(s[ct][2], 1);
      float x3 = __shfl_xor(s[ct][3], 1);
      float lo0 = ev ? s[ct][0] : x2;
      float hi0 = ev ? x0 : s[ct][2];
      float lo1 = ev ? s[ct][1] : x3;
      float hi1 = ev ? x1 : s[ct][3];
      int r0 = ev ? 0 : 2, r1 = ev ? 1 : 3;
      unsigned w0 = ((unsigned)f2bf_bits(hi0) << 16) | f2bf_bits(lo0);
      unsigned w1 = ((unsigned)f2bf_bits(hi1) << 16) | f2bf_bits(lo1);
      *(unsigned*)(pl + (quad * 4 + r0) * 72 + ct * 16 + cbase) = w0;
      *(unsigned*)(pl + (quad * 4 + r1) * 72 + ct * 16 + cbase) = w1;
    }
    asm volatile("" ::: "memory");
    short8 pf0 = *(const short8*)(pl + c * 72 + quad * 8);
    short8 pf1 = *(const short8*)(pl + c * 72 + 32 + quad * 8);
    // --- PV + l accumulate ---
#pragma unroll
    for (int t = 0; t < 4; t++) {
      acc_o[t] = __builtin_amdgcn_mfma_f32_16x16x32_bf16(pf0, vf[t][0], acc_o[t], 0, 0, 0);
      acc_o[t] = __builtin_amdgcn_mfma_f32_16x16x32_bf16(pf1, vf[t][1], acc_o[t], 0, 0, 0);
    }
    acc_o[4] = __builtin_amdgcn_mfma_f32_16x16x32_bf16(pf0, onesf, acc_o[4], 0, 0, 0);
    acc_o[4] = __builtin_amdgcn_mfma_f32_16x16x32_bf16(pf1, onesf, acc_o[4], 0, 0, 0);
  }
  // --- epilogue: /l, transpose C[row=l][col=d] -> LDS [16 l][66 d] -> o_t ---
  float linv[4];
#pragma unroll
  for (int r = 0; r < 4; r++)
    linv[r] = 1.0f / __shfl(acc_o[4][r], lane & 48);  // col-0 lane of this quad
  asm volatile("" ::: "memory");
#pragma unroll
  for (int t = 0; t < 4; t++) {
    int us[4];
#pragma unroll
    for (int r = 0; r < 4; r++) us[r] = f2bf_bits(acc_o[t][r] * linv[r]);
    int xv0 = __shfl_xor(us[0], 1);
    int xv1 = __shfl_xor(us[1], 1);
    int xv2 = __shfl_xor(us[2], 1);
    int xv3 = __shfl_xor(us[3], 1);
    if (ev) {
      *(int*)(pl + (quad * 4 + 0) * 66 + t * 16 + c) = (xv0 << 16) | us[0];
      *(int*)(pl + (quad * 4 + 1) * 66 + t * 16 + c) = (xv1 << 16) | us[1];
    } else {
      *(int*)(pl + (quad * 4 + 2) * 66 + t * 16 + (c - 1)) = (us[2] << 16) | xv2;
      *(int*)(pl + (quad * 4 + 3) * 66 + t * 16 + (c - 1)) = (us[3] << 16) | xv3;
    }
  }
  asm volatile("" ::: "memory");
  int row = lane >> 2, seg = lane & 3;
  short8 o0 = *(const short8*)(pl + row * 66 + seg * 16);
  short8 o1 = *(const short8*)(pl + row * 66 + seg * 16 + 8);
  int n = nh >> 2, h = nh & 3;
  short* dst = (short*)ot + ((size_t)n * 1600 + bx * 16 + row) * 256 + h * 64 + seg * 16;
  *(short8*)(dst) = o0;
  *(short8*)(dst + 8) = o1;
}

// ---------------------------------------------------------------------------
// K3: (1,9) conv as MFMA GEMM: C[m=l(16/wave)][n=co(64)] over K=ci(256)x9taps.
// A-frags from o_t[n][l][ci] global (L2), per-lane tap-validity mask.
// B-frags from fragment-major Wt. Epilogue: BN1 + bias + residual x + relu
// -> y[n][co][l] (8B reg stores) and y_t[n][l][ci] (wave-private LDS transp).
// grid (50,16), block 128 (2 waves). No __syncthreads.
// ---------------------------------------------------------------------------
__global__ void k_conv9(const bf16* __restrict__ ot, const bf16* __restrict__ Wt,
                        const float* __restrict__ bo, const float* __restrict__ g1,
                        const float* __restrict__ be1, const float* __restrict__ mu1,
                        const float* __restrict__ va1, const float* __restrict__ x,
                        bf16* __restrict__ y, bf16* __restrict__ yt) {
  __shared__ short tl[2][16 * 66];
  int wv = threadIdx.x >> 6;
  int lane = threadIdx.x & 63;
  int quad = lane >> 4, c = lane & 15;
  int n = blockIdx.y;
  int l0 = blockIdx.x * 32 + wv * 16;
  int la = l0 + c;           // this lane's A-row (m = c)
  int va = la % 25;
  const short* obase = (const short*)ot + (size_t)n * 409600;
  const short* wbase = (const short*)Wt;
  f32x4 acc[4] = {};
  for (int r = 0; r < 9; r++) {
    int sh = r - 4;
    bool valid = (unsigned)(va + sh) < 25u;
    int lp = la + sh;
    lp = max(0, min(1599, lp));
    const short* arow = obase + (size_t)lp * 256 + quad * 8;
    const short* wrow = wbase + (size_t)r * 8 * 4 * 64 * 8 + lane * 8;
    short8 z8 = {0, 0, 0, 0, 0, 0, 0, 0};
#pragma unroll 4
    for (int kc = 0; kc < 8; kc++) {
      short8 af = *(const short8*)(arow + kc * 32);
      af = valid ? af : z8;
      const short* wk = wrow + kc * 4 * 64 * 8;
      short8 b0 = *(const short8*)(wk);
      short8 b1 = *(const short8*)(wk + 512);
      short8 b2 = *(const short8*)(wk + 1024);
      short8 b3 = *(const short8*)(wk + 1536);
      acc[0] = __builtin_amdgcn_mfma_f32_16x16x32_bf16(af, b0, acc[0], 0, 0, 0);
      acc[1] = __builtin_amdgcn_mfma_f32_16x16x32_bf16(af, b1, acc[1], 0, 0, 0);
      acc[2] = __builtin_amdgcn_mfma_f32_16x16x32_bf16(af, b2, acc[2], 0, 0, 0);
      acc[3] = __builtin_amdgcn_mfma_f32_16x16x32_bf16(af, b3, acc[3], 0, 0, 0);
    }
  }
  // --- epilogue: lane owns co = cot*16+c, rows l = l0+quad*4+{0..3} ---
  short* tlw = &tl[wv][0];
  float outv[4][4];
#pragma unroll
  for (int cot = 0; cot < 4; cot++) {
    int co = cot * 16 + c;
    float inv = g1[co] * rsqrtf(va1[co] + 1e-5f);
    float add = be1[co] - mu1[co] * inv + bo[co] * inv;
    f32x4 xr = *(const f32x4*)(x + (size_t)(n * 64 + co) * 1600 + l0 + quad * 4);
    us4 yb;
#pragma unroll
    for (int rr = 0; rr < 4; rr++) {
      float vv = fmaxf(acc[cot][rr] * inv + add + xr[rr], 0.f);
      outv[cot][rr] = vv;
      yb[rr] = f2bf_bits(vv);
    }
    *(us4*)((short*)y + (size_t)(n * 64 + co) * 1600 + l0 + quad * 4) = yb;
  }
  // --- y_t transpose via wave-private LDS [16 l][66 ci] ---
  asm volatile("" ::: "memory");
  bool ev = (c & 1) == 0;
#pragma unroll
  for (int cot = 0; cot < 4; cot++) {
    int us[4];
#pragma unroll
    for (int rr = 0; rr < 4; rr++) us[rr] = f2bf_bits(outv[cot][rr]);
    int xv0 = __shfl_xor(us[0], 1);
    int xv1 = __shfl_xor(us[1], 1);
    int xv2 = __shfl_xor(us[2], 1);
    int xv3 = __shfl_xor(us[3], 1);
    if (ev) {
      *(int*)(tlw + (quad * 4 + 0) * 66 + cot * 16 + c) = (xv0 << 16) | us[0];
      *(int*)(tlw + (quad * 4 + 1) * 66 + cot * 16 + c) = (xv1 << 16) | us[1];
    } else {
      *(int*)(tlw + (quad * 4 + 2) * 66 + cot * 16 + (c - 1)) = (us[2] << 16) | xv2;
      *(int*)(tlw + (quad * 4 + 3) * 66 + cot * 16 + (c - 1)) = (us[3] << 16) | xv3;
    }
  }
  asm volatile("" ::: "memory");
  int row = lane >> 2, seg = lane & 3;
  short8 y0 = *(const short8*)(tlw + row * 66 + seg * 16);
  short8 y1 = *(const short8*)(tlw + row * 66 + seg * 16 + 8);
  short* yd = (short*)yt + ((size_t)n * 1600 + l0 + row) * 64 + seg * 16;
  *(short8*)(yd) = y0;
  *(short8*)(yd + 8) = y1;
}

// ---------------------------------------------------------------------------
// K4: 1x1 conv as MFMA GEMM (K=64) + BN2 + residual(y) + relu -> d_out fp32.
// grid (50,16), block 128 (2 waves). No LDS, no barriers.
// ---------------------------------------------------------------------------
__global__ void k_ff(const bf16* __restrict__ yt, const bf16* __restrict__ WfT,
                     const bf16* __restrict__ y, const float* __restrict__ bff,
                     const float* __restrict__ g2, const float* __restrict__ be2,
                     const float* __restrict__ mu2, const float* __restrict__ va2,
                     float* __restrict__ out) {
  int wv = threadIdx.x >> 6;
  int lane = threadIdx.x & 63;
  int quad = lane >> 4, c = lane & 15;
  int n = blockIdx.y;
  int l0 = blockIdx.x * 32 + wv * 16;
  const short* arow = (const short*)yt + ((size_t)n * 1600 + l0 + c) * 64 + quad * 8;
  const short* wbase = (const short*)WfT + lane * 8;
  f32x4 acc[4] = {};
#pragma unroll
  for (int kc = 0; kc < 2; kc++) {
    short8 af = *(const short8*)(arow + kc * 32);
    const short* wk = wbase + kc * 2048;
    short8 b0 = *(const short8*)(wk);
    short8 b1 = *(const short8*)(wk + 512);
    short8 b2 = *(const short8*)(wk + 1024);
    short8 b3 = *(const short8*)(wk + 1536);
    acc[0] = __builtin_amdgcn_mfma_f32_16x16x32_bf16(af, b0, acc[0], 0, 0, 0);
    acc[1] = __builtin_amdgcn_mfma_f32_16x16x32_bf16(af, b1, acc[1], 0, 0, 0);
    acc[2] = __builtin_amdgcn_mfma_f32_16x16x32_bf16(af, b2, acc[2], 0, 0, 0);
    acc[3] = __builtin_amdgcn_mfma_f32_16x16x32_bf16(af, b3, acc[3], 0, 0, 0);
  }
#pragma unroll
  for (int cot = 0; cot < 4; cot++) {
    int co = cot * 16 + c;
    float inv = g2[co] * rsqrtf(va2[co] + 1e-5f);
    float add = be2[co] - mu2[co] * inv + bff[co] * inv;
    size_t base = (size_t)(n * 64 + co) * 1600 + l0 + quad * 4;
    us4 yr = *(const us4*)((const short*)y + base);
    f32x4 ov;
#pragma unroll
    for (int rr = 0; rr < 4; rr++) {
      unsigned short ub = yr[rr];
      float yv;
      *(unsigned*)&yv = ((unsigned)ub) << 16;  // bf16 bits -> f32
      ov[rr] = fmaxf(acc[cot][rr] * inv + add + yv, 0.f);
    }
    *(f32x4*)(out + base) = ov;
  }
}

extern "C" void kernel_launch(void* const* d_in, const int* in_sizes, int n_in,
                              void* d_out, int out_size, void* d_ws, size_t ws_size,
                              hipStream_t stream) {
  const float* x   = (const float*)d_in[0];
  const float* Wq  = (const float*)d_in[1];
  const float* bq  = (const float*)d_in[2];
  const float* Wo  = (const float*)d_in[3];
  const float* bo  = (const float*)d_in[4];
  const float* g1  = (const float*)d_in[5];
  const float* be1 = (const float*)d_in[6];
  const float* mu1 = (const float*)d_in[7];
  const float* va1 = (const float*)d_in[8];
  const float* Wf  = (const float*)d_in[9];
  const float* bff = (const float*)d_in[10];
  const float* g2  = (const float*)d_in[11];
  const float* be2 = (const float*)d_in[12];
  const float* mu2 = (const float*)d_in[13];
  const float* va2 = (const float*)d_in[14];

  // ws (bf16 elems): q,k [nh][l][64]; vt [nh][64][l]; ot [n][l][256];
  //                  y [n][64][l]; yt [n][l][64]; Wt 147456; WfT 4096  (~46.5MB)
  const size_t QKV = (size_t)64 * 1600 * 64;
  bf16* qw  = (bf16*)d_ws;
  bf16* kw  = qw + QKV;
  bf16* vtw = kw + QKV;
  bf16* otw = vtw + QKV;
  bf16* yw  = otw + QKV;
  bf16* ytw = yw + 1638400;
  bf16* Wt  = ytw + 1638400;
  bf16* WfT = Wt + 147456;

  k_prep<<<576, 256, 0, stream>>>(Wo, Wf, Wt, WfT);
  k_qkv<<<3200, 256, 0, stream>>>(x, Wq, bq, qw, kw, vtw);
  dim3 ga(25, 64);
  k_attn<<<ga, 256, 0, stream>>>(qw, kw, vtw, otw);
  dim3 gc(50, 16);
  k_conv9<<<gc, 128, 0, stream>>>(otw, Wt, bo, g1, be1, mu1, va1, x, yw, ytw);
  k_ff<<<gc, 128, 0, stream>>>(ytw, WfT, yw, bff, g2, be2, mu2, va2, (float*)d_out);
}

// Round 8
// 309.543 us; speedup vs baseline: 1.5287x; 1.5287x over previous
//
#include <hip/hip_runtime.h>
#include <hip/hip_bf16.h>

// Problem constants (fixed by setup_inputs)
#define NB 16     // batch
#define CC 64     // channels
#define TT 64
#define VV 25
#define LL 1600   // T*V
#define HH 4
#define DD 64
#define NH 64     // N*H

// Dtype contract (established rounds 0-3): d_in fp32, d_out fp32,
// tolerance bf16-grade (2% * max|ref|) -> internal bf16 pipeline OK.

typedef __hip_bfloat16 bf16;
typedef __attribute__((ext_vector_type(8))) short short8;
typedef __attribute__((ext_vector_type(4))) float f32x4;
typedef __attribute__((ext_vector_type(4))) unsigned short us4;

__device__ __forceinline__ float b2f(bf16 v) { return __bfloat162float(v); }
__device__ __forceinline__ unsigned short f2bf_bits(float f) {
  bf16 h = __float2bfloat16(f);
  return *(unsigned short*)&h;
}

// ---------------------------------------------------------------------------
// K0: weight prep (unchanged).
// ---------------------------------------------------------------------------
__global__ void k_prep(const float* __restrict__ Wo, const float* __restrict__ Wf,
                       bf16* __restrict__ Wt, bf16* __restrict__ WfT) {
  int i = blockIdx.x * 256 + threadIdx.x;
  if (i < 147456) {
    int j = i & 7, lane = (i >> 3) & 63, cot = (i >> 9) & 3;
    int kc = (i >> 11) & 7, r = i >> 14;
    int co = cot * 16 + (lane & 15);
    int ci = kc * 32 + (lane >> 4) * 8 + j;
    Wt[i] = __float2bfloat16(Wo[(co * 256 + ci) * 9 + r]);
  }
  if (i < 4096) {
    int j = i & 7, lane = (i >> 3) & 63, cot = (i >> 9) & 3, kc = (i >> 11) & 1;
    int co = cot * 16 + (lane & 15);
    int ci = kc * 32 + (lane >> 4) * 8 + j;
    WfT[i] = __float2bfloat16(Wf[co * 64 + ci]);
  }
}

// ---------------------------------------------------------------------------
// K1: qkv projection (unchanged). q pre-scaled by 0.125*log2(e).
// ---------------------------------------------------------------------------
__global__ void k_qkv(const float* __restrict__ x, const float* __restrict__ Wq,
                      const float* __restrict__ bq,
                      bf16* __restrict__ q, bf16* __restrict__ k,
                      bf16* __restrict__ vt) {
  __shared__ float xr[64 * 8];  // [c][ll]
  int n = blockIdx.x / 200;
  int l0 = (blockIdx.x % 200) * 8;
  int tid = threadIdx.x;
  for (int idx = tid; idx < 512; idx += 256) {
    int c = idx >> 3, ll = idx & 7;
    xr[idx] = x[(size_t)(n * 64 + c) * 1600 + l0 + ll];
  }
  __syncthreads();
  int j0 = tid;  // 0..255
  float acc[3][8];
#pragma unroll
  for (int s = 0; s < 3; s++) {
    float bv = bq[s * 256 + j0];
#pragma unroll
    for (int ll = 0; ll < 8; ll++) acc[s][ll] = bv;
  }
  for (int c = 0; c < 64; c++) {
    float w0 = Wq[c * 768 + j0];
    float w1 = Wq[c * 768 + 256 + j0];
    float w2 = Wq[c * 768 + 512 + j0];
    const float* xc = &xr[c * 8];
#pragma unroll
    for (int ll = 0; ll < 8; ll++) {
      float xv = xc[ll];
      acc[0][ll] += xv * w0;
      acc[1][ll] += xv * w1;
      acc[2][ll] += xv * w2;
    }
  }
  int h = j0 >> 6, d = j0 & 63;
  const float QSCALE = 0.125f * 1.44269504f;  // 1/sqrt(64) * log2(e)
#pragma unroll
  for (int ll = 0; ll < 8; ll++) {
    size_t off = ((size_t)(n * 4 + h) * 1600 + (l0 + ll)) * 64 + d;
    q[off] = __float2bfloat16(acc[0][ll] * QSCALE);
    k[off] = __float2bfloat16(acc[1][ll]);
  }
  unsigned short vb[8];
#pragma unroll
  for (int ll = 0; ll < 8; ll++) vb[ll] = f2bf_bits(acc[2][ll]);
  *(short8*)((short*)vt + ((size_t)(n * 4 + h) * 64 + d) * 1600 + l0) =
      *(short8*)vb;
}

// ---------------------------------------------------------------------------
// K2: MFMA flash attention, round-8 structure.
// Blocks of 128 thr (2 waves); each wave owns 32 Q-rows (two accumulating
// 16-row tiles). grid (25,64). K tile [64 kv][64 d] staged cooperatively in
// LDS (row-padded to 72 shorts: unpadded 64-short rows put all 16 frag-read
// lanes on the same bank = 16-way conflict). m97-style 2-barrier loop:
// staging loads for kt+1 issued right after barrier 2, consumed by ds_write
// a full iteration later -> global latency never exposed to the MFMA chain.
// V frags direct from global, issued before the exp2/P-transpose phase.
// Fixed-max softmax p = exp2(s-8) (uniform scale cancels in sum(p*v)/sum(p)).
// ---------------------------------------------------------------------------
__global__ __launch_bounds__(128, 2)
void k_attn(const bf16* __restrict__ q, const bf16* __restrict__ k,
            const bf16* __restrict__ vt, bf16* __restrict__ ot) {
  __shared__ short kbuf[64 * 72];    // K tile, padded rows
  __shared__ short pl_all[2][2304];  // per wave: 2 tiles of [16 m][72 j]
  int tid = threadIdx.x;
  int wv = tid >> 6, lane = tid & 63;
  int quad = lane >> 4, c = lane & 15;
  int nh = blockIdx.y;
  int l0 = blockIdx.x * 64 + wv * 32;  // wave's rows: tiles at l0, l0+16
  short* pl = pl_all[wv];

  // Q fragments for both tiles (live whole kernel)
  const short* qbase = (const short*)q + ((size_t)nh * 1600 + l0 + c) * 64 + quad * 8;
  short8 qf[2][2];
  qf[0][0] = *(const short8*)(qbase);
  qf[0][1] = *(const short8*)(qbase + 32);
  qf[1][0] = *(const short8*)(qbase + 16 * 64);
  qf[1][1] = *(const short8*)(qbase + 16 * 64 + 32);

  short ob = (c == 0) ? (short)0x3F80 : (short)0;  // bf16 1.0 in col 0
  short8 onesf = {ob, ob, ob, ob, ob, ob, ob, ob};

  f32x4 acc[2][5] = {};  // per tile: 4 d-tiles + l-tile (ones-trick)

  const short* kg = (const short*)k + (size_t)nh * 102400;
  const short* vg = (const short*)vt + (size_t)nh * 102400;
  bool ev = (c & 1) == 0;
  int cbase = c & ~1;

  // prologue: issue staging loads for kt=0 (4x16B per thread, coalesced)
  short8 sk[4];
  {
    const short8* gk = (const short8*)kg;
#pragma unroll
    for (int i = 0; i < 4; i++) sk[i] = gk[tid + i * 128];
  }

  for (int kt = 0; kt < 25; kt++) {
    __syncthreads();  // all reads of kbuf (iter kt-1) complete
    {
#pragma unroll
      for (int i = 0; i < 4; i++) {
        int ch = tid + i * 128;  // chunk: row=ch>>3, off=ch&7
        *(short8*)(kbuf + (ch >> 3) * 72 + (ch & 7) * 8) = sk[i];
      }
    }
    __syncthreads();  // kbuf(kt) visible
    if (kt < 24) {    // issue loads for kt+1; drain during this iteration
      const short8* gk = (const short8*)(kg + (kt + 1) * 4096);
#pragma unroll
      for (int i = 0; i < 4; i++) sk[i] = gk[tid + i * 128];
    }
    // --- K frags from LDS (shared across both tiles) + QK MFMAs ---
    f32x4 s[2][4];
#pragma unroll
    for (int ct = 0; ct < 4; ct++) {
      short8 kf0 = *(const short8*)(kbuf + (ct * 16 + c) * 72 + quad * 8);
      short8 kf1 = *(const short8*)(kbuf + (ct * 16 + c) * 72 + 32 + quad * 8);
      f32x4 z0 = {0.f, 0.f, 0.f, 0.f}, z1 = {0.f, 0.f, 0.f, 0.f};
      z0 = __builtin_amdgcn_mfma_f32_16x16x32_bf16(qf[0][0], kf0, z0, 0, 0, 0);
      z0 = __builtin_amdgcn_mfma_f32_16x16x32_bf16(qf[0][1], kf1, z0, 0, 0, 0);
      z1 = __builtin_amdgcn_mfma_f32_16x16x32_bf16(qf[1][0], kf0, z1, 0, 0, 0);
      z1 = __builtin_amdgcn_mfma_f32_16x16x32_bf16(qf[1][1], kf1, z1, 0, 0, 0);
      s[0][ct] = z0;
      s[1][ct] = z1;
    }
    // --- V frags (global, L2): issued here, drain under exp2/P-transpose ---
    short8 vf[4][2];
#pragma unroll
    for (int ct = 0; ct < 4; ct++) {
      const short* p0 = vg + (size_t)(ct * 16 + c) * 1600 + kt * 64 + quad * 8;
      vf[ct][0] = *(const short8*)(p0);
      vf[ct][1] = *(const short8*)(p0 + 32);
    }
    // --- p = exp2(s - 8), both tiles ---
#pragma unroll
    for (int tt = 0; tt < 2; tt++)
#pragma unroll
      for (int ct = 0; ct < 4; ct++)
#pragma unroll
        for (int r = 0; r < 4; r++) s[tt][ct][r] = exp2f(s[tt][ct][r] - 8.0f);
    // --- P: C-layout -> A-layout LDS (wave-private regions, both tiles) ---
    asm volatile("" ::: "memory");
#pragma unroll
    for (int tt = 0; tt < 2; tt++) {
      short* plt = pl + tt * 1152;
#pragma unroll
      for (int ct = 0; ct < 4; ct++) {
        float x0 = __shfl_xor(s[tt][ct][0], 1);
        float x1 = __shfl_xor(s[tt][ct][1], 1);
        float x2 = __shfl_xor(s[tt][ct][2], 1);
        float x3 = __shfl_xor(s[tt][ct][3], 1);
        float lo0 = ev ? s[tt][ct][0] : x2;
        float hi0 = ev ? x0 : s[tt][ct][2];
        float lo1 = ev ? s[tt][ct][1] : x3;
        float hi1 = ev ? x1 : s[tt][ct][3];
        int r0 = ev ? 0 : 2, r1 = ev ? 1 : 3;
        unsigned w0 = ((unsigned)f2bf_bits(hi0) << 16) | f2bf_bits(lo0);
        unsigned w1 = ((unsigned)f2bf_bits(hi1) << 16) | f2bf_bits(lo1);
        *(unsigned*)(plt + (quad * 4 + r0) * 72 + ct * 16 + cbase) = w0;
        *(unsigned*)(plt + (quad * 4 + r1) * 72 + ct * 16 + cbase) = w1;
      }
    }
    asm volatile("" ::: "memory");
    short8 pf[2][2];
#pragma unroll
    for (int tt = 0; tt < 2; tt++) {
      pf[tt][0] = *(const short8*)(pl + tt * 1152 + c * 72 + quad * 8);
      pf[tt][1] = *(const short8*)(pl + tt * 1152 + c * 72 + 32 + quad * 8);
    }
    // --- PV + l accumulate ---
#pragma unroll
    for (int ct = 0; ct < 4; ct++) {
#pragma unroll
      for (int tt = 0; tt < 2; tt++) {
        acc[tt][ct] = __builtin_amdgcn_mfma_f32_16x16x32_bf16(pf[tt][0], vf[ct][0], acc[tt][ct], 0, 0, 0);
        acc[tt][ct] = __builtin_amdgcn_mfma_f32_16x16x32_bf16(pf[tt][1], vf[ct][1], acc[tt][ct], 0, 0, 0);
      }
    }
#pragma unroll
    for (int tt = 0; tt < 2; tt++) {
      acc[tt][4] = __builtin_amdgcn_mfma_f32_16x16x32_bf16(pf[tt][0], onesf, acc[tt][4], 0, 0, 0);
      acc[tt][4] = __builtin_amdgcn_mfma_f32_16x16x32_bf16(pf[tt][1], onesf, acc[tt][4], 0, 0, 0);
    }
  }
  // --- epilogue per tile: /l, transpose via pl, coalesced stores to o_t ---
  int n = nh >> 2, h = nh & 3;
#pragma unroll
  for (int tt = 0; tt < 2; tt++) {
    float linv[4];
#pragma unroll
    for (int r = 0; r < 4; r++)
      linv[r] = 1.0f / __shfl(acc[tt][4][r], lane & 48);  // col-0 lane of quad
    asm volatile("" ::: "memory");
#pragma unroll
    for (int t = 0; t < 4; t++) {
      int us_[4];
#pragma unroll
      for (int r = 0; r < 4; r++) us_[r] = f2bf_bits(acc[tt][t][r] * linv[r]);
      int xv0 = __shfl_xor(us_[0], 1);
      int xv1 = __shfl_xor(us_[1], 1);
      int xv2 = __shfl_xor(us_[2], 1);
      int xv3 = __shfl_xor(us_[3], 1);
      if (ev) {
        *(int*)(pl + (quad * 4 + 0) * 66 + t * 16 + c) = (xv0 << 16) | us_[0];
        *(int*)(pl + (quad * 4 + 1) * 66 + t * 16 + c) = (xv1 << 16) | us_[1];
      } else {
        *(int*)(pl + (quad * 4 + 2) * 66 + t * 16 + (c - 1)) = (us_[2] << 16) | xv2;
        *(int*)(pl + (quad * 4 + 3) * 66 + t * 16 + (c - 1)) = (us_[3] << 16) | xv3;
      }
    }
    asm volatile("" ::: "memory");
    int row = lane >> 2, seg = lane & 3;
    short8 o0 = *(const short8*)(pl + row * 66 + seg * 16);
    short8 o1 = *(const short8*)(pl + row * 66 + seg * 16 + 8);
    short* dst = (short*)ot + ((size_t)n * 1600 + l0 + tt * 16 + row) * 256 + h * 64 + seg * 16;
    *(short8*)(dst) = o0;
    *(short8*)(dst + 8) = o1;
    asm volatile("" ::: "memory");  // pl reused by next tile
  }
}

// ---------------------------------------------------------------------------
// K3: (1,9) conv as MFMA GEMM (unchanged from round 5 — 905 -> ~30 us).
// ---------------------------------------------------------------------------
__global__ void k_conv9(const bf16* __restrict__ ot, const bf16* __restrict__ Wt,
                        const float* __restrict__ bo, const float* __restrict__ g1,
                        const float* __restrict__ be1, const float* __restrict__ mu1,
                        const float* __restrict__ va1, const float* __restrict__ x,
                        bf16* __restrict__ y, bf16* __restrict__ yt) {
  __shared__ short tl[2][16 * 66];
  int wv = threadIdx.x >> 6;
  int lane = threadIdx.x & 63;
  int quad = lane >> 4, c = lane & 15;
  int n = blockIdx.y;
  int l0 = blockIdx.x * 32 + wv * 16;
  int la = l0 + c;
  int va = la % 25;
  const short* obase = (const short*)ot + (size_t)n * 409600;
  const short* wbase = (const short*)Wt;
  f32x4 acc[4] = {};
  for (int r = 0; r < 9; r++) {
    int sh = r - 4;
    bool valid = (unsigned)(va + sh) < 25u;
    int lp = la + sh;
    lp = max(0, min(1599, lp));
    const short* arow = obase + (size_t)lp * 256 + quad * 8;
    const short* wrow = wbase + (size_t)r * 8 * 4 * 64 * 8 + lane * 8;
    short8 z8 = {0, 0, 0, 0, 0, 0, 0, 0};
#pragma unroll 4
    for (int kc = 0; kc < 8; kc++) {
      short8 af = *(const short8*)(arow + kc * 32);
      af = valid ? af : z8;
      const short* wk = wrow + kc * 4 * 64 * 8;
      short8 b0 = *(const short8*)(wk);
      short8 b1 = *(const short8*)(wk + 512);
      short8 b2 = *(const short8*)(wk + 1024);
      short8 b3 = *(const short8*)(wk + 1536);
      acc[0] = __builtin_amdgcn_mfma_f32_16x16x32_bf16(af, b0, acc[0], 0, 0, 0);
      acc[1] = __builtin_amdgcn_mfma_f32_16x16x32_bf16(af, b1, acc[1], 0, 0, 0);
      acc[2] = __builtin_amdgcn_mfma_f32_16x16x32_bf16(af, b2, acc[2], 0, 0, 0);
      acc[3] = __builtin_amdgcn_mfma_f32_16x16x32_bf16(af, b3, acc[3], 0, 0, 0);
    }
  }
  short* tlw = &tl[wv][0];
  float outv[4][4];
#pragma unroll
  for (int cot = 0; cot < 4; cot++) {
    int co = cot * 16 + c;
    float inv = g1[co] * rsqrtf(va1[co] + 1e-5f);
    float add = be1[co] - mu1[co] * inv + bo[co] * inv;
    f32x4 xr = *(const f32x4*)(x + (size_t)(n * 64 + co) * 1600 + l0 + quad * 4);
    us4 yb;
#pragma unroll
    for (int rr = 0; rr < 4; rr++) {
      float vv = fmaxf(acc[cot][rr] * inv + add + xr[rr], 0.f);
      outv[cot][rr] = vv;
      yb[rr] = f2bf_bits(vv);
    }
    *(us4*)((short*)y + (size_t)(n * 64 + co) * 1600 + l0 + quad * 4) = yb;
  }
  asm volatile("" ::: "memory");
  bool ev = (c & 1) == 0;
#pragma unroll
  for (int cot = 0; cot < 4; cot++) {
    int us_[4];
#pragma unroll
    for (int rr = 0; rr < 4; rr++) us_[rr] = f2bf_bits(outv[cot][rr]);
    int xv0 = __shfl_xor(us_[0], 1);
    int xv1 = __shfl_xor(us_[1], 1);
    int xv2 = __shfl_xor(us_[2], 1);
    int xv3 = __shfl_xor(us_[3], 1);
    if (ev) {
      *(int*)(tlw + (quad * 4 + 0) * 66 + cot * 16 + c) = (xv0 << 16) | us_[0];
      *(int*)(tlw + (quad * 4 + 1) * 66 + cot * 16 + c) = (xv1 << 16) | us_[1];
    } else {
      *(int*)(tlw + (quad * 4 + 2) * 66 + cot * 16 + (c - 1)) = (us_[2] << 16) | xv2;
      *(int*)(tlw + (quad * 4 + 3) * 66 + cot * 16 + (c - 1)) = (us_[3] << 16) | xv3;
    }
  }
  asm volatile("" ::: "memory");
  int row = lane >> 2, seg = lane & 3;
  short8 y0 = *(const short8*)(tlw + row * 66 + seg * 16);
  short8 y1 = *(const short8*)(tlw + row * 66 + seg * 16 + 8);
  short* yd = (short*)yt + ((size_t)n * 1600 + l0 + row) * 64 + seg * 16;
  *(short8*)(yd) = y0;
  *(short8*)(yd + 8) = y1;
}

// ---------------------------------------------------------------------------
// K4: 1x1 conv as MFMA GEMM (unchanged).
// ---------------------------------------------------------------------------
__global__ void k_ff(const bf16* __restrict__ yt, const bf16* __restrict__ WfT,
                     const bf16* __restrict__ y, const float* __restrict__ bff,
                     const float* __restrict__ g2, const float* __restrict__ be2,
                     const float* __restrict__ mu2, const float* __restrict__ va2,
                     float* __restrict__ out) {
  int wv = threadIdx.x >> 6;
  int lane = threadIdx.x & 63;
  int quad = lane >> 4, c = lane & 15;
  int n = blockIdx.y;
  int l0 = blockIdx.x * 32 + wv * 16;
  const short* arow = (const short*)yt + ((size_t)n * 1600 + l0 + c) * 64 + quad * 8;
  const short* wbase = (const short*)WfT + lane * 8;
  f32x4 acc[4] = {};
#pragma unroll
  for (int kc = 0; kc < 2; kc++) {
    short8 af = *(const short8*)(arow + kc * 32);
    const short* wk = wbase + kc * 2048;
    short8 b0 = *(const short8*)(wk);
    short8 b1 = *(const short8*)(wk + 512);
    short8 b2 = *(const short8*)(wk + 1024);
    short8 b3 = *(const short8*)(wk + 1536);
    acc[0] = __builtin_amdgcn_mfma_f32_16x16x32_bf16(af, b0, acc[0], 0, 0, 0);
    acc[1] = __builtin_amdgcn_mfma_f32_16x16x32_bf16(af, b1, acc[1], 0, 0, 0);
    acc[2] = __builtin_amdgcn_mfma_f32_16x16x32_bf16(af, b2, acc[2], 0, 0, 0);
    acc[3] = __builtin_amdgcn_mfma_f32_16x16x32_bf16(af, b3, acc[3], 0, 0, 0);
  }
#pragma unroll
  for (int cot = 0; cot < 4; cot++) {
    int co = cot * 16 + c;
    float inv = g2[co] * rsqrtf(va2[co] + 1e-5f);
    float add = be2[co] - mu2[co] * inv + bff[co] * inv;
    size_t base = (size_t)(n * 64 + co) * 1600 + l0 + quad * 4;
    us4 yr = *(const us4*)((const short*)y + base);
    f32x4 ov;
#pragma unroll
    for (int rr = 0; rr < 4; rr++) {
      unsigned short ub = yr[rr];
      float yv;
      *(unsigned*)&yv = ((unsigned)ub) << 16;  // bf16 bits -> f32
      ov[rr] = fmaxf(acc[cot][rr] * inv + add + yv, 0.f);
    }
    *(f32x4*)(out + base) = ov;
  }
}

extern "C" void kernel_launch(void* const* d_in, const int* in_sizes, int n_in,
                              void* d_out, int out_size, void* d_ws, size_t ws_size,
                              hipStream_t stream) {
  const float* x   = (const float*)d_in[0];
  const float* Wq  = (const float*)d_in[1];
  const float* bq  = (const float*)d_in[2];
  const float* Wo  = (const float*)d_in[3];
  const float* bo  = (const float*)d_in[4];
  const float* g1  = (const float*)d_in[5];
  const float* be1 = (const float*)d_in[6];
  const float* mu1 = (const float*)d_in[7];
  const float* va1 = (const float*)d_in[8];
  const float* Wf  = (const float*)d_in[9];
  const float* bff = (const float*)d_in[10];
  const float* g2  = (const float*)d_in[11];
  const float* be2 = (const float*)d_in[12];
  const float* mu2 = (const float*)d_in[13];
  const float* va2 = (const float*)d_in[14];

  // ws (bf16 elems): q,k [nh][l][64]; vt [nh][64][l]; ot [n][l][256];
  //                  y [n][64][l]; yt [n][l][64]; Wt 147456; WfT 4096  (~46.5MB)
  const size_t QKV = (size_t)64 * 1600 * 64;
  bf16* qw  = (bf16*)d_ws;
  bf16* kw  = qw + QKV;
  bf16* vtw = kw + QKV;
  bf16* otw = vtw + QKV;
  bf16* yw  = otw + QKV;
  bf16* ytw = yw + 1638400;
  bf16* Wt  = ytw + 1638400;
  bf16* WfT = Wt + 147456;

  k_prep<<<576, 256, 0, stream>>>(Wo, Wf, Wt, WfT);
  k_qkv<<<3200, 256, 0, stream>>>(x, Wq, bq, qw, kw, vtw);
  dim3 ga(25, 64);
  k_attn<<<ga, 128, 0, stream>>>(qw, kw, vtw, otw);
  dim3 gc(50, 16);
  k_conv9<<<gc, 128, 0, stream>>>(otw, Wt, bo, g1, be1, mu1, va1, x, yw, ytw);
  k_ff<<<gc, 128, 0, stream>>>(ytw, WfT, yw, bff, g2, be2, mu2, va2, (float*)d_out);
}

// Round 9
// 275.348 us; speedup vs baseline: 1.7186x; 1.1242x over previous
//
#include <hip/hip_runtime.h>
#include <hip/hip_bf16.h>

// Problem constants (fixed by setup_inputs)
#define NB 16     // batch
#define CC 64     // channels
#define TT 64
#define VV 25
#define LL 1600   // T*V
#define HH 4
#define DD 64
#define NH 64     // N*H

// Dtype contract (established rounds 0-3): d_in fp32, d_out fp32,
// tolerance bf16-grade (2% * max|ref|) -> internal bf16 pipeline OK.

typedef __hip_bfloat16 bf16;
typedef __attribute__((ext_vector_type(8))) short short8;
typedef __attribute__((ext_vector_type(4))) float f32x4;
typedef __attribute__((ext_vector_type(4))) unsigned short us4;

__device__ __forceinline__ float b2f(bf16 v) { return __bfloat162float(v); }
__device__ __forceinline__ unsigned short f2bf_bits(float f) {
  bf16 h = __float2bfloat16(f);
  return *(unsigned short*)&h;
}
// xor-1 lane exchange via DPP quad_perm [1,0,3,2] (0xB1): VALU, not LDS.
__device__ __forceinline__ float dppx1(float x) {
  return __int_as_float(
      __builtin_amdgcn_mov_dpp(__float_as_int(x), 0xB1, 0xF, 0xF, true));
}
__device__ __forceinline__ int dppx1i(int x) {
  return __builtin_amdgcn_mov_dpp(x, 0xB1, 0xF, 0xF, true);
}

// ---------------------------------------------------------------------------
// K0: weight prep (unchanged).
// ---------------------------------------------------------------------------
__global__ void k_prep(const float* __restrict__ Wo, const float* __restrict__ Wf,
                       bf16* __restrict__ Wt, bf16* __restrict__ WfT) {
  int i = blockIdx.x * 256 + threadIdx.x;
  if (i < 147456) {
    int j = i & 7, lane = (i >> 3) & 63, cot = (i >> 9) & 3;
    int kc = (i >> 11) & 7, r = i >> 14;
    int co = cot * 16 + (lane & 15);
    int ci = kc * 32 + (lane >> 4) * 8 + j;
    Wt[i] = __float2bfloat16(Wo[(co * 256 + ci) * 9 + r]);
  }
  if (i < 4096) {
    int j = i & 7, lane = (i >> 3) & 63, cot = (i >> 9) & 3, kc = (i >> 11) & 1;
    int co = cot * 16 + (lane & 15);
    int ci = kc * 32 + (lane >> 4) * 8 + j;
    WfT[i] = __float2bfloat16(Wf[co * 64 + ci]);
  }
}

// ---------------------------------------------------------------------------
// K1: qkv projection (unchanged). q pre-scaled by 0.125*log2(e).
// ---------------------------------------------------------------------------
__global__ void k_qkv(const float* __restrict__ x, const float* __restrict__ Wq,
                      const float* __restrict__ bq,
                      bf16* __restrict__ q, bf16* __restrict__ k,
                      bf16* __restrict__ vt) {
  __shared__ float xr[64 * 8];  // [c][ll]
  int n = blockIdx.x / 200;
  int l0 = (blockIdx.x % 200) * 8;
  int tid = threadIdx.x;
  for (int idx = tid; idx < 512; idx += 256) {
    int c = idx >> 3, ll = idx & 7;
    xr[idx] = x[(size_t)(n * 64 + c) * 1600 + l0 + ll];
  }
  __syncthreads();
  int j0 = tid;  // 0..255
  float acc[3][8];
#pragma unroll
  for (int s = 0; s < 3; s++) {
    float bv = bq[s * 256 + j0];
#pragma unroll
    for (int ll = 0; ll < 8; ll++) acc[s][ll] = bv;
  }
  for (int c = 0; c < 64; c++) {
    float w0 = Wq[c * 768 + j0];
    float w1 = Wq[c * 768 + 256 + j0];
    float w2 = Wq[c * 768 + 512 + j0];
    const float* xc = &xr[c * 8];
#pragma unroll
    for (int ll = 0; ll < 8; ll++) {
      float xv = xc[ll];
      acc[0][ll] += xv * w0;
      acc[1][ll] += xv * w1;
      acc[2][ll] += xv * w2;
    }
  }
  int h = j0 >> 6, d = j0 & 63;
  const float QSCALE = 0.125f * 1.44269504f;  // 1/sqrt(64) * log2(e)
#pragma unroll
  for (int ll = 0; ll < 8; ll++) {
    size_t off = ((size_t)(n * 4 + h) * 1600 + (l0 + ll)) * 64 + d;
    q[off] = __float2bfloat16(acc[0][ll] * QSCALE);
    k[off] = __float2bfloat16(acc[1][ll]);
  }
  unsigned short vb[8];
#pragma unroll
  for (int ll = 0; ll < 8; ll++) vb[ll] = f2bf_bits(acc[2][ll]);
  *(short8*)((short*)vt + ((size_t)(n * 4 + h) * 64 + d) * 1600 + l0) =
      *(short8*)vb;
}

// ---------------------------------------------------------------------------
// K2: MFMA flash attention, round-9.
// 2 waves/block, 32 Q-rows/wave, grid (25,64). K tile staged in LDS with
// 1-iteration prefetch (round-8 structure, 159 us). Round-9 deltas:
//  (a) P-transpose pairing via DPP mov (0xB1) instead of __shfl_xor -> the
//      32 ds_swizzle LDS ops per wave-iter become VALU.
//  (b) V fragment loads hoisted to right after barrier 2 -> drain window
//      spans K-frag reads + QK MFMAs + exp2 + pack (~700+ cyc, covers HBM
//      misses; FETCH showed 3x compulsory => many V loads miss L2).
//  (c) QK accumulator initialized to -8.0 => p = exp2(s) directly (softmax
//      bias folded into MFMA C-init; uniform scale cancels in sum(p*v)/sum(p)).
// ---------------------------------------------------------------------------
__global__ __launch_bounds__(128, 2)
void k_attn(const bf16* __restrict__ q, const bf16* __restrict__ k,
            const bf16* __restrict__ vt, bf16* __restrict__ ot) {
  __shared__ short kbuf[64 * 72];    // K tile, padded rows
  __shared__ short pl_all[2][2304];  // per wave: 2 tiles of [16 m][72 j]
  int tid = threadIdx.x;
  int wv = tid >> 6, lane = tid & 63;
  int quad = lane >> 4, c = lane & 15;
  int nh = blockIdx.y;
  int l0 = blockIdx.x * 64 + wv * 32;  // wave's rows: tiles at l0, l0+16
  short* pl = pl_all[wv];

  // Q fragments for both tiles (live whole kernel)
  const short* qbase = (const short*)q + ((size_t)nh * 1600 + l0 + c) * 64 + quad * 8;
  short8 qf[2][2];
  qf[0][0] = *(const short8*)(qbase);
  qf[0][1] = *(const short8*)(qbase + 32);
  qf[1][0] = *(const short8*)(qbase + 16 * 64);
  qf[1][1] = *(const short8*)(qbase + 16 * 64 + 32);

  short ob = (c == 0) ? (short)0x3F80 : (short)0;  // bf16 1.0 in col 0
  short8 onesf = {ob, ob, ob, ob, ob, ob, ob, ob};

  f32x4 acc[2][5] = {};  // per tile: 4 d-tiles + l-tile (ones-trick)

  const short* kg = (const short*)k + (size_t)nh * 102400;
  const short* vg = (const short*)vt + (size_t)nh * 102400;
  bool ev = (c & 1) == 0;
  int cbase = c & ~1;

  // prologue: issue staging loads for kt=0 (4x16B per thread, coalesced)
  short8 sk[4];
  {
    const short8* gk = (const short8*)kg;
#pragma unroll
    for (int i = 0; i < 4; i++) sk[i] = gk[tid + i * 128];
  }

  for (int kt = 0; kt < 25; kt++) {
    __syncthreads();  // all reads of kbuf (iter kt-1) complete
    {
#pragma unroll
      for (int i = 0; i < 4; i++) {
        int ch = tid + i * 128;  // chunk: row=ch>>3, off=ch&7
        *(short8*)(kbuf + (ch >> 3) * 72 + (ch & 7) * 8) = sk[i];
      }
    }
    __syncthreads();  // kbuf(kt) visible
    // --- V frags (global, L2/HBM): issued FIRST, drain under QK+exp2+pack ---
    short8 vf[4][2];
#pragma unroll
    for (int ct = 0; ct < 4; ct++) {
      const short* p0 = vg + (size_t)(ct * 16 + c) * 1600 + kt * 64 + quad * 8;
      vf[ct][0] = *(const short8*)(p0);
      vf[ct][1] = *(const short8*)(p0 + 32);
    }
    if (kt < 24) {    // issue K staging loads for kt+1; drain this iteration
      const short8* gk = (const short8*)(kg + (kt + 1) * 4096);
#pragma unroll
      for (int i = 0; i < 4; i++) sk[i] = gk[tid + i * 128];
    }
    // --- K frags from LDS (shared across both tiles) + QK MFMAs (C=-8) ---
    f32x4 s[2][4];
#pragma unroll
    for (int ct = 0; ct < 4; ct++) {
      short8 kf0 = *(const short8*)(kbuf + (ct * 16 + c) * 72 + quad * 8);
      short8 kf1 = *(const short8*)(kbuf + (ct * 16 + c) * 72 + 32 + quad * 8);
      f32x4 z0 = {-8.f, -8.f, -8.f, -8.f}, z1 = {-8.f, -8.f, -8.f, -8.f};
      z0 = __builtin_amdgcn_mfma_f32_16x16x32_bf16(qf[0][0], kf0, z0, 0, 0, 0);
      z0 = __builtin_amdgcn_mfma_f32_16x16x32_bf16(qf[0][1], kf1, z0, 0, 0, 0);
      z1 = __builtin_amdgcn_mfma_f32_16x16x32_bf16(qf[1][0], kf0, z1, 0, 0, 0);
      z1 = __builtin_amdgcn_mfma_f32_16x16x32_bf16(qf[1][1], kf1, z1, 0, 0, 0);
      s[0][ct] = z0;
      s[1][ct] = z1;
    }
    // --- p = exp2(s), both tiles (bias already in accumulator init) ---
#pragma unroll
    for (int tt = 0; tt < 2; tt++)
#pragma unroll
      for (int ct = 0; ct < 4; ct++)
#pragma unroll
        for (int r = 0; r < 4; r++) s[tt][ct][r] = exp2f(s[tt][ct][r]);
    // --- P: C-layout -> A-layout LDS (wave-private, DPP pairing) ---
    asm volatile("" ::: "memory");
#pragma unroll
    for (int tt = 0; tt < 2; tt++) {
      short* plt = pl + tt * 1152;
#pragma unroll
      for (int ct = 0; ct < 4; ct++) {
        float x0 = dppx1(s[tt][ct][0]);
        float x1 = dppx1(s[tt][ct][1]);
        float x2 = dppx1(s[tt][ct][2]);
        float x3 = dppx1(s[tt][ct][3]);
        float lo0 = ev ? s[tt][ct][0] : x2;
        float hi0 = ev ? x0 : s[tt][ct][2];
        float lo1 = ev ? s[tt][ct][1] : x3;
        float hi1 = ev ? x1 : s[tt][ct][3];
        int r0 = ev ? 0 : 2, r1 = ev ? 1 : 3;
        unsigned w0 = ((unsigned)f2bf_bits(hi0) << 16) | f2bf_bits(lo0);
        unsigned w1 = ((unsigned)f2bf_bits(hi1) << 16) | f2bf_bits(lo1);
        *(unsigned*)(plt + (quad * 4 + r0) * 72 + ct * 16 + cbase) = w0;
        *(unsigned*)(plt + (quad * 4 + r1) * 72 + ct * 16 + cbase) = w1;
      }
    }
    asm volatile("" ::: "memory");
    short8 pf[2][2];
#pragma unroll
    for (int tt = 0; tt < 2; tt++) {
      pf[tt][0] = *(const short8*)(pl + tt * 1152 + c * 72 + quad * 8);
      pf[tt][1] = *(const short8*)(pl + tt * 1152 + c * 72 + 32 + quad * 8);
    }
    // --- PV + l accumulate ---
#pragma unroll
    for (int ct = 0; ct < 4; ct++) {
#pragma unroll
      for (int tt = 0; tt < 2; tt++) {
        acc[tt][ct] = __builtin_amdgcn_mfma_f32_16x16x32_bf16(pf[tt][0], vf[ct][0], acc[tt][ct], 0, 0, 0);
        acc[tt][ct] = __builtin_amdgcn_mfma_f32_16x16x32_bf16(pf[tt][1], vf[ct][1], acc[tt][ct], 0, 0, 0);
      }
    }
#pragma unroll
    for (int tt = 0; tt < 2; tt++) {
      acc[tt][4] = __builtin_amdgcn_mfma_f32_16x16x32_bf16(pf[tt][0], onesf, acc[tt][4], 0, 0, 0);
      acc[tt][4] = __builtin_amdgcn_mfma_f32_16x16x32_bf16(pf[tt][1], onesf, acc[tt][4], 0, 0, 0);
    }
  }
  // --- epilogue per tile: /l, transpose via pl, coalesced stores to o_t ---
  int n = nh >> 2, h = nh & 3;
#pragma unroll
  for (int tt = 0; tt < 2; tt++) {
    float linv[4];
#pragma unroll
    for (int r = 0; r < 4; r++)
      linv[r] = 1.0f / __shfl(acc[tt][4][r], lane & 48);  // col-0 lane of quad
    asm volatile("" ::: "memory");
#pragma unroll
    for (int t = 0; t < 4; t++) {
      int us_[4];
#pragma unroll
      for (int r = 0; r < 4; r++) us_[r] = f2bf_bits(acc[tt][t][r] * linv[r]);
      int xv0 = dppx1i(us_[0]);
      int xv1 = dppx1i(us_[1]);
      int xv2 = dppx1i(us_[2]);
      int xv3 = dppx1i(us_[3]);
      if (ev) {
        *(int*)(pl + (quad * 4 + 0) * 66 + t * 16 + c) = (xv0 << 16) | us_[0];
        *(int*)(pl + (quad * 4 + 1) * 66 + t * 16 + c) = (xv1 << 16) | us_[1];
      } else {
        *(int*)(pl + (quad * 4 + 2) * 66 + t * 16 + (c - 1)) = (us_[2] << 16) | xv2;
        *(int*)(pl + (quad * 4 + 3) * 66 + t * 16 + (c - 1)) = (us_[3] << 16) | xv3;
      }
    }
    asm volatile("" ::: "memory");
    int row = lane >> 2, seg = lane & 3;
    short8 o0 = *(const short8*)(pl + row * 66 + seg * 16);
    short8 o1 = *(const short8*)(pl + row * 66 + seg * 16 + 8);
    short* dst = (short*)ot + ((size_t)n * 1600 + l0 + tt * 16 + row) * 256 + h * 64 + seg * 16;
    *(short8*)(dst) = o0;
    *(short8*)(dst + 8) = o1;
    asm volatile("" ::: "memory");  // pl reused by next tile
  }
}

// ---------------------------------------------------------------------------
// K3: (1,9) conv as MFMA GEMM (round-5 structure; DPP pairing in transpose).
// ---------------------------------------------------------------------------
__global__ void k_conv9(const bf16* __restrict__ ot, const bf16* __restrict__ Wt,
                        const float* __restrict__ bo, const float* __restrict__ g1,
                        const float* __restrict__ be1, const float* __restrict__ mu1,
                        const float* __restrict__ va1, const float* __restrict__ x,
                        bf16* __restrict__ y, bf16* __restrict__ yt) {
  __shared__ short tl[2][16 * 66];
  int wv = threadIdx.x >> 6;
  int lane = threadIdx.x & 63;
  int quad = lane >> 4, c = lane & 15;
  int n = blockIdx.y;
  int l0 = blockIdx.x * 32 + wv * 16;
  int la = l0 + c;
  int va = la % 25;
  const short* obase = (const short*)ot + (size_t)n * 409600;
  const short* wbase = (const short*)Wt;
  f32x4 acc[4] = {};
  for (int r = 0; r < 9; r++) {
    int sh = r - 4;
    bool valid = (unsigned)(va + sh) < 25u;
    int lp = la + sh;
    lp = max(0, min(1599, lp));
    const short* arow = obase + (size_t)lp * 256 + quad * 8;
    const short* wrow = wbase + (size_t)r * 8 * 4 * 64 * 8 + lane * 8;
    short8 z8 = {0, 0, 0, 0, 0, 0, 0, 0};
#pragma unroll 4
    for (int kc = 0; kc < 8; kc++) {
      short8 af = *(const short8*)(arow + kc * 32);
      af = valid ? af : z8;
      const short* wk = wrow + kc * 4 * 64 * 8;
      short8 b0 = *(const short8*)(wk);
      short8 b1 = *(const short8*)(wk + 512);
      short8 b2 = *(const short8*)(wk + 1024);
      short8 b3 = *(const short8*)(wk + 1536);
      acc[0] = __builtin_amdgcn_mfma_f32_16x16x32_bf16(af, b0, acc[0], 0, 0, 0);
      acc[1] = __builtin_amdgcn_mfma_f32_16x16x32_bf16(af, b1, acc[1], 0, 0, 0);
      acc[2] = __builtin_amdgcn_mfma_f32_16x16x32_bf16(af, b2, acc[2], 0, 0, 0);
      acc[3] = __builtin_amdgcn_mfma_f32_16x16x32_bf16(af, b3, acc[3], 0, 0, 0);
    }
  }
  short* tlw = &tl[wv][0];
  float outv[4][4];
#pragma unroll
  for (int cot = 0; cot < 4; cot++) {
    int co = cot * 16 + c;
    float inv = g1[co] * rsqrtf(va1[co] + 1e-5f);
    float add = be1[co] - mu1[co] * inv + bo[co] * inv;
    f32x4 xr = *(const f32x4*)(x + (size_t)(n * 64 + co) * 1600 + l0 + quad * 4);
    us4 yb;
#pragma unroll
    for (int rr = 0; rr < 4; rr++) {
      float vv = fmaxf(acc[cot][rr] * inv + add + xr[rr], 0.f);
      outv[cot][rr] = vv;
      yb[rr] = f2bf_bits(vv);
    }
    *(us4*)((short*)y + (size_t)(n * 64 + co) * 1600 + l0 + quad * 4) = yb;
  }
  asm volatile("" ::: "memory");
  bool ev = (c & 1) == 0;
#pragma unroll
  for (int cot = 0; cot < 4; cot++) {
    int us_[4];
#pragma unroll
    for (int rr = 0; rr < 4; rr++) us_[rr] = f2bf_bits(outv[cot][rr]);
    int xv0 = dppx1i(us_[0]);
    int xv1 = dppx1i(us_[1]);
    int xv2 = dppx1i(us_[2]);
    int xv3 = dppx1i(us_[3]);
    if (ev) {
      *(int*)(tlw + (quad * 4 + 0) * 66 + cot * 16 + c) = (xv0 << 16) | us_[0];
      *(int*)(tlw + (quad * 4 + 1) * 66 + cot * 16 + c) = (xv1 << 16) | us_[1];
    } else {
      *(int*)(tlw + (quad * 4 + 2) * 66 + cot * 16 + (c - 1)) = (us_[2] << 16) | xv2;
      *(int*)(tlw + (quad * 4 + 3) * 66 + cot * 16 + (c - 1)) = (us_[3] << 16) | xv3;
    }
  }
  asm volatile("" ::: "memory");
  int row = lane >> 2, seg = lane & 3;
  short8 y0 = *(const short8*)(tlw + row * 66 + seg * 16);
  short8 y1 = *(const short8*)(tlw + row * 66 + seg * 16 + 8);
  short* yd = (short*)yt + ((size_t)n * 1600 + l0 + row) * 64 + seg * 16;
  *(short8*)(yd) = y0;
  *(short8*)(yd + 8) = y1;
}

// ---------------------------------------------------------------------------
// K4: 1x1 conv as MFMA GEMM (unchanged).
// ---------------------------------------------------------------------------
__global__ void k_ff(const bf16* __restrict__ yt, const bf16* __restrict__ WfT,
                     const bf16* __restrict__ y, const float* __restrict__ bff,
                     const float* __restrict__ g2, const float* __restrict__ be2,
                     const float* __restrict__ mu2, const float* __restrict__ va2,
                     float* __restrict__ out) {
  int wv = threadIdx.x >> 6;
  int lane = threadIdx.x & 63;
  int quad = lane >> 4, c = lane & 15;
  int n = blockIdx.y;
  int l0 = blockIdx.x * 32 + wv * 16;
  const short* arow = (const short*)yt + ((size_t)n * 1600 + l0 + c) * 64 + quad * 8;
  const short* wbase = (const short*)WfT + lane * 8;
  f32x4 acc[4] = {};
#pragma unroll
  for (int kc = 0; kc < 2; kc++) {
    short8 af = *(const short8*)(arow + kc * 32);
    const short* wk = wbase + kc * 2048;
    short8 b0 = *(const short8*)(wk);
    short8 b1 = *(const short8*)(wk + 512);
    short8 b2 = *(const short8*)(wk + 1024);
    short8 b3 = *(const short8*)(wk + 1536);
    acc[0] = __builtin_amdgcn_mfma_f32_16x16x32_bf16(af, b0, acc[0], 0, 0, 0);
    acc[1] = __builtin_amdgcn_mfma_f32_16x16x32_bf16(af, b1, acc[1], 0, 0, 0);
    acc[2] = __builtin_amdgcn_mfma_f32_16x16x32_bf16(af, b2, acc[2], 0, 0, 0);
    acc[3] = __builtin_amdgcn_mfma_f32_16x16x32_bf16(af, b3, acc[3], 0, 0, 0);
  }
#pragma unroll
  for (int cot = 0; cot < 4; cot++) {
    int co = cot * 16 + c;
    float inv = g2[co] * rsqrtf(va2[co] + 1e-5f);
    float add = be2[co] - mu2[co] * inv + bff[co] * inv;
    size_t base = (size_t)(n * 64 + co) * 1600 + l0 + quad * 4;
    us4 yr = *(const us4*)((const short*)y + base);
    f32x4 ov;
#pragma unroll
    for (int rr = 0; rr < 4; rr++) {
      unsigned short ub = yr[rr];
      float yv;
      *(unsigned*)&yv = ((unsigned)ub) << 16;  // bf16 bits -> f32
      ov[rr] = fmaxf(acc[cot][rr] * inv + add + yv, 0.f);
    }
    *(f32x4*)(out + base) = ov;
  }
}

extern "C" void kernel_launch(void* const* d_in, const int* in_sizes, int n_in,
                              void* d_out, int out_size, void* d_ws, size_t ws_size,
                              hipStream_t stream) {
  const float* x   = (const float*)d_in[0];
  const float* Wq  = (const float*)d_in[1];
  const float* bq  = (const float*)d_in[2];
  const float* Wo  = (const float*)d_in[3];
  const float* bo  = (const float*)d_in[4];
  const float* g1  = (const float*)d_in[5];
  const float* be1 = (const float*)d_in[6];
  const float* mu1 = (const float*)d_in[7];
  const float* va1 = (const float*)d_in[8];
  const float* Wf  = (const float*)d_in[9];
  const float* bff = (const float*)d_in[10];
  const float* g2  = (const float*)d_in[11];
  const float* be2 = (const float*)d_in[12];
  const float* mu2 = (const float*)d_in[13];
  const float* va2 = (const float*)d_in[14];

  // ws (bf16 elems): q,k [nh][l][64]; vt [nh][64][l]; ot [n][l][256];
  //                  y [n][64][l]; yt [n][l][64]; Wt 147456; WfT 4096  (~46.5MB)
  const size_t QKV = (size_t)64 * 1600 * 64;
  bf16* qw  = (bf16*)d_ws;
  bf16* kw  = qw + QKV;
  bf16* vtw = kw + QKV;
  bf16* otw = vtw + QKV;
  bf16* yw  = otw + QKV;
  bf16* ytw = yw + 1638400;
  bf16* Wt  = ytw + 1638400;
  bf16* WfT = Wt + 147456;

  k_prep<<<576, 256, 0, stream>>>(Wo, Wf, Wt, WfT);
  k_qkv<<<3200, 256, 0, stream>>>(x, Wq, bq, qw, kw, vtw);
  dim3 ga(25, 64);
  k_attn<<<ga, 128, 0, stream>>>(qw, kw, vtw, otw);
  dim3 gc(50, 16);
  k_conv9<<<gc, 128, 0, stream>>>(otw, Wt, bo, g1, be1, mu1, va1, x, yw, ytw);
  k_ff<<<gc, 128, 0, stream>>>(ytw, WfT, yw, bff, g2, be2, mu2, va2, (float*)d_out);
}

// Round 10
// 263.694 us; speedup vs baseline: 1.7945x; 1.0442x over previous
//
#include <hip/hip_runtime.h>
#include <hip/hip_bf16.h>

// Problem constants (fixed by setup_inputs)
#define NB 16     // batch
#define CC 64     // channels
#define TT 64
#define VV 25
#define LL 1600   // T*V
#define HH 4
#define DD 64
#define NH 64     // N*H

// Dtype contract (established rounds 0-3): d_in fp32, d_out fp32,
// tolerance bf16-grade (2% * max|ref|) -> internal bf16 pipeline OK.

typedef __hip_bfloat16 bf16;
typedef __attribute__((ext_vector_type(8))) short short8;
typedef __attribute__((ext_vector_type(4))) float f32x4;
typedef __attribute__((ext_vector_type(4))) unsigned short us4;

__device__ __forceinline__ float b2f(bf16 v) { return __bfloat162float(v); }
__device__ __forceinline__ unsigned short f2bf_bits(float f) {
  bf16 h = __float2bfloat16(f);
  return *(unsigned short*)&h;
}
// xor-1 lane exchange via DPP quad_perm [1,0,3,2] (0xB1): VALU, not LDS.
__device__ __forceinline__ float dppx1(float x) {
  return __int_as_float(
      __builtin_amdgcn_mov_dpp(__float_as_int(x), 0xB1, 0xF, 0xF, true));
}
__device__ __forceinline__ int dppx1i(int x) {
  return __builtin_amdgcn_mov_dpp(x, 0xB1, 0xF, 0xF, true);
}

// ---------------------------------------------------------------------------
// K0: weight prep. Wt (conv9) + WfT (ff) as before; NEW: WqT fragment-major:
//   WqT[((half*48+nt)*64+lane)*8+jj] = Wq[(half*32+(lane>>4)*8+jj)*768 + nt*16+(lane&15)]
// grid 576, block 256.
// ---------------------------------------------------------------------------
__global__ void k_prep(const float* __restrict__ Wo, const float* __restrict__ Wf,
                       const float* __restrict__ Wq,
                       bf16* __restrict__ Wt, bf16* __restrict__ WfT,
                       bf16* __restrict__ WqT) {
  int i = blockIdx.x * 256 + threadIdx.x;
  if (i < 147456) {
    int j = i & 7, lane = (i >> 3) & 63, cot = (i >> 9) & 3;
    int kc = (i >> 11) & 7, r = i >> 14;
    int co = cot * 16 + (lane & 15);
    int ci = kc * 32 + (lane >> 4) * 8 + j;
    Wt[i] = __float2bfloat16(Wo[(co * 256 + ci) * 9 + r]);
  }
  if (i < 4096) {
    int j = i & 7, lane = (i >> 3) & 63, cot = (i >> 9) & 3, kc = (i >> 11) & 1;
    int co = cot * 16 + (lane & 15);
    int ci = kc * 32 + (lane >> 4) * 8 + j;
    WfT[i] = __float2bfloat16(Wf[co * 64 + ci]);
  }
  if (i < 49152) {
    int jj = i & 7, lane = (i >> 3) & 63, g = i >> 9;  // g 0..95
    int nt = g % 48, half = g / 48;
    int ch = half * 32 + (lane >> 4) * 8 + jj;
    int j = nt * 16 + (lane & 15);
    WqT[i] = __float2bfloat16(Wq[ch * 768 + j]);
  }
}

// ---------------------------------------------------------------------------
// K1: qkv projection as MFMA GEMM. One wave per 16 l-rows per n: grid 1600,
// block 64. C[m=l(16)][n=j(768)] over K=64 channels. A-tile staged in LDS
// (x fp32 -> bf16, [l][c] padded 72), B-frags from fragment-major WqT (L2
// broadcast). Epilogue: q/k via 16x64 tile-transpose in LDS (DPP pairing),
// v written directly (C cols are d, rows are 4 consecutive l -> 8B stores).
// q pre-scaled by 0.125*log2(e) (incl. bias) for base-2 softmax.
// ---------------------------------------------------------------------------
__global__ __launch_bounds__(64)
void k_qkv(const float* __restrict__ x, const bf16* __restrict__ WqT,
           const float* __restrict__ bq,
           bf16* __restrict__ q, bf16* __restrict__ k, bf16* __restrict__ vt) {
  __shared__ short xa[16 * 72];  // A-tile [16 l][64 c] (+pad)
  __shared__ short tr[16 * 66];  // transpose buffer for q/k epilogue
  int lane = threadIdx.x;
  int quad = lane >> 4, c = lane & 15;
  int n = blockIdx.x / 100;
  int l0 = (blockIdx.x % 100) * 16;
  bool ev = (c & 1) == 0;
  int cbase = c & ~1;

  // --- stage x[n][cc][l0+l] -> xa[l][cc] bf16; lane=(quad,l=c) ---
  {
    int l = c;
    const float* xb = x + (size_t)n * 102400 + (size_t)(quad * 16) * 1600 + l0 + l;
    unsigned short vb[16];
#pragma unroll
    for (int i = 0; i < 16; i++) vb[i] = f2bf_bits(xb[(size_t)i * 1600]);
    unsigned wrds[8];
#pragma unroll
    for (int i = 0; i < 8; i++)
      wrds[i] = ((unsigned)vb[2 * i + 1] << 16) | vb[2 * i];
    *(short8*)(xa + l * 72 + quad * 16) = *(short8*)&wrds[0];
    *(short8*)(xa + l * 72 + quad * 16 + 8) = *(short8*)&wrds[4];
  }
  asm volatile("" ::: "memory");
  short8 af0 = *(const short8*)(xa + c * 72 + quad * 8);        // k = 0..31
  short8 af1 = *(const short8*)(xa + c * 72 + 32 + quad * 8);   // k = 32..63

  const short* wq0 = (const short*)WqT;
  const float QSCALE = 0.125f * 1.44269504f;

  // --- q (s=0) and k (s=1): 4 h-groups x 4 tiles, tile-transpose epilogue ---
#pragma unroll
  for (int s = 0; s < 2; s++) {
#pragma unroll
    for (int h = 0; h < 4; h++) {
      asm volatile("" ::: "memory");
#pragma unroll
      for (int t = 0; t < 4; t++) {
        int nt = s * 16 + h * 4 + t;
        float bv = bq[nt * 16 + c];
        f32x4 z = {bv, bv, bv, bv};
        short8 b0 = *(const short8*)(wq0 + ((size_t)nt * 64 + lane) * 8);
        short8 b1 = *(const short8*)(wq0 + ((size_t)(48 + nt) * 64 + lane) * 8);
        z = __builtin_amdgcn_mfma_f32_16x16x32_bf16(af0, b0, z, 0, 0, 0);
        z = __builtin_amdgcn_mfma_f32_16x16x32_bf16(af1, b1, z, 0, 0, 0);
        if (s == 0) {
#pragma unroll
          for (int r = 0; r < 4; r++) z[r] *= QSCALE;
        }
        int us_[4];
#pragma unroll
        for (int r = 0; r < 4; r++) us_[r] = f2bf_bits(z[r]);
        int xv0 = dppx1i(us_[0]);
        int xv1 = dppx1i(us_[1]);
        int xv2 = dppx1i(us_[2]);
        int xv3 = dppx1i(us_[3]);
        if (ev) {
          *(int*)(tr + (quad * 4 + 0) * 66 + t * 16 + c) = (xv0 << 16) | us_[0];
          *(int*)(tr + (quad * 4 + 1) * 66 + t * 16 + c) = (xv1 << 16) | us_[1];
        } else {
          *(int*)(tr + (quad * 4 + 2) * 66 + t * 16 + (c - 1)) = (us_[2] << 16) | xv2;
          *(int*)(tr + (quad * 4 + 3) * 66 + t * 16 + (c - 1)) = (us_[3] << 16) | xv3;
        }
      }
      asm volatile("" ::: "memory");
      int row = lane >> 2, seg = lane & 3;
      short8 o0 = *(const short8*)(tr + row * 66 + seg * 16);
      short8 o1 = *(const short8*)(tr + row * 66 + seg * 16 + 8);
      short* dstp = (short*)(s == 0 ? q : k);
      short* dst = dstp + ((size_t)(n * 4 + h) * 1600 + l0 + row) * 64 + seg * 16;
      *(short8*)(dst) = o0;
      *(short8*)(dst + 8) = o1;
    }
  }
  // --- v (s=2): direct stores, vt[nh][d][l] (lane owns d=t*16+c, 4 l's) ---
#pragma unroll
  for (int h = 0; h < 4; h++) {
#pragma unroll
    for (int t = 0; t < 4; t++) {
      int nt = 32 + h * 4 + t;
      float bv = bq[nt * 16 + c];
      f32x4 z = {bv, bv, bv, bv};
      short8 b0 = *(const short8*)(wq0 + ((size_t)nt * 64 + lane) * 8);
      short8 b1 = *(const short8*)(wq0 + ((size_t)(48 + nt) * 64 + lane) * 8);
      z = __builtin_amdgcn_mfma_f32_16x16x32_bf16(af0, b0, z, 0, 0, 0);
      z = __builtin_amdgcn_mfma_f32_16x16x32_bf16(af1, b1, z, 0, 0, 0);
      us4 pk;
#pragma unroll
      for (int r = 0; r < 4; r++) pk[r] = f2bf_bits(z[r]);
      *(us4*)((short*)vt + ((size_t)((n * 4 + h) * 64 + t * 16 + c)) * 1600 +
              l0 + quad * 4) = pk;
    }
  }
}

// ---------------------------------------------------------------------------
// K2: MFMA flash attention (round-9 structure) + XCD-aware swizzle: all 25
// Q-tile blocks of an nh share (bid % 8) -> same XCD L2; 8 nh-streams/XCD x
// 400 KB = 3.2 MB < 4 MB -> K/V re-reads become L2 hits (round-9 FETCH was
// 8.6x compulsory from cross-XCD refetch). grid 1600 linear, block 128.
// ---------------------------------------------------------------------------
__global__ __launch_bounds__(128, 2)
void k_attn(const bf16* __restrict__ q, const bf16* __restrict__ k,
            const bf16* __restrict__ vt, bf16* __restrict__ ot) {
  __shared__ short kbuf[64 * 72];    // K tile, padded rows
  __shared__ short pl_all[2][2304];  // per wave: 2 tiles of [16 m][72 j]
  int tid = threadIdx.x;
  int wv = tid >> 6, lane = tid & 63;
  int quad = lane >> 4, c = lane & 15;
  int bid = blockIdx.x;              // 0..1599
  int xcd = bid & 7;
  int slot = bid >> 3;               // 0..199
  int qt = slot % 25;                // Q-tile index
  int nh = (slot / 25) * 8 + xcd;    // 0..63, nh%8 == bid%8
  int l0 = qt * 64 + wv * 32;        // wave's rows: tiles at l0, l0+16
  short* pl = pl_all[wv];

  const short* qbase = (const short*)q + ((size_t)nh * 1600 + l0 + c) * 64 + quad * 8;
  short8 qf[2][2];
  qf[0][0] = *(const short8*)(qbase);
  qf[0][1] = *(const short8*)(qbase + 32);
  qf[1][0] = *(const short8*)(qbase + 16 * 64);
  qf[1][1] = *(const short8*)(qbase + 16 * 64 + 32);

  short ob = (c == 0) ? (short)0x3F80 : (short)0;  // bf16 1.0 in col 0
  short8 onesf = {ob, ob, ob, ob, ob, ob, ob, ob};

  f32x4 acc[2][5] = {};  // per tile: 4 d-tiles + l-tile (ones-trick)

  const short* kg = (const short*)k + (size_t)nh * 102400;
  const short* vg = (const short*)vt + (size_t)nh * 102400;
  bool ev = (c & 1) == 0;
  int cbase = c & ~1;

  // prologue: issue staging loads for kt=0 (4x16B per thread, coalesced)
  short8 sk[4];
  {
    const short8* gk = (const short8*)kg;
#pragma unroll
    for (int i = 0; i < 4; i++) sk[i] = gk[tid + i * 128];
  }

  for (int kt = 0; kt < 25; kt++) {
    __syncthreads();  // all reads of kbuf (iter kt-1) complete
    {
#pragma unroll
      for (int i = 0; i < 4; i++) {
        int ch = tid + i * 128;  // chunk: row=ch>>3, off=ch&7
        *(short8*)(kbuf + (ch >> 3) * 72 + (ch & 7) * 8) = sk[i];
      }
    }
    __syncthreads();  // kbuf(kt) visible
    // --- V frags: issued FIRST, drain under QK+exp2+pack ---
    short8 vf[4][2];
#pragma unroll
    for (int ct = 0; ct < 4; ct++) {
      const short* p0 = vg + (size_t)(ct * 16 + c) * 1600 + kt * 64 + quad * 8;
      vf[ct][0] = *(const short8*)(p0);
      vf[ct][1] = *(const short8*)(p0 + 32);
    }
    if (kt < 24) {    // issue K staging loads for kt+1; drain this iteration
      const short8* gk = (const short8*)(kg + (kt + 1) * 4096);
#pragma unroll
      for (int i = 0; i < 4; i++) sk[i] = gk[tid + i * 128];
    }
    // --- K frags from LDS + QK MFMAs (C init = -8 folds softmax bias) ---
    f32x4 s[2][4];
#pragma unroll
    for (int ct = 0; ct < 4; ct++) {
      short8 kf0 = *(const short8*)(kbuf + (ct * 16 + c) * 72 + quad * 8);
      short8 kf1 = *(const short8*)(kbuf + (ct * 16 + c) * 72 + 32 + quad * 8);
      f32x4 z0 = {-8.f, -8.f, -8.f, -8.f}, z1 = {-8.f, -8.f, -8.f, -8.f};
      z0 = __builtin_amdgcn_mfma_f32_16x16x32_bf16(qf[0][0], kf0, z0, 0, 0, 0);
      z0 = __builtin_amdgcn_mfma_f32_16x16x32_bf16(qf[0][1], kf1, z0, 0, 0, 0);
      z1 = __builtin_amdgcn_mfma_f32_16x16x32_bf16(qf[1][0], kf0, z1, 0, 0, 0);
      z1 = __builtin_amdgcn_mfma_f32_16x16x32_bf16(qf[1][1], kf1, z1, 0, 0, 0);
      s[0][ct] = z0;
      s[1][ct] = z1;
    }
    // --- p = exp2(s), both tiles ---
#pragma unroll
    for (int tt = 0; tt < 2; tt++)
#pragma unroll
      for (int ct = 0; ct < 4; ct++)
#pragma unroll
        for (int r = 0; r < 4; r++) s[tt][ct][r] = exp2f(s[tt][ct][r]);
    // --- P: C-layout -> A-layout LDS (wave-private, DPP pairing) ---
    asm volatile("" ::: "memory");
#pragma unroll
    for (int tt = 0; tt < 2; tt++) {
      short* plt = pl + tt * 1152;
#pragma unroll
      for (int ct = 0; ct < 4; ct++) {
        float x0 = dppx1(s[tt][ct][0]);
        float x1 = dppx1(s[tt][ct][1]);
        float x2 = dppx1(s[tt][ct][2]);
        float x3 = dppx1(s[tt][ct][3]);
        float lo0 = ev ? s[tt][ct][0] : x2;
        float hi0 = ev ? x0 : s[tt][ct][2];
        float lo1 = ev ? s[tt][ct][1] : x3;
        float hi1 = ev ? x1 : s[tt][ct][3];
        int r0 = ev ? 0 : 2, r1 = ev ? 1 : 3;
        unsigned w0 = ((unsigned)f2bf_bits(hi0) << 16) | f2bf_bits(lo0);
        unsigned w1 = ((unsigned)f2bf_bits(hi1) << 16) | f2bf_bits(lo1);
        *(unsigned*)(plt + (quad * 4 + r0) * 72 + ct * 16 + cbase) = w0;
        *(unsigned*)(plt + (quad * 4 + r1) * 72 + ct * 16 + cbase) = w1;
      }
    }
    asm volatile("" ::: "memory");
    short8 pf[2][2];
#pragma unroll
    for (int tt = 0; tt < 2; tt++) {
      pf[tt][0] = *(const short8*)(pl + tt * 1152 + c * 72 + quad * 8);
      pf[tt][1] = *(const short8*)(pl + tt * 1152 + c * 72 + 32 + quad * 8);
    }
    // --- PV + l accumulate ---
#pragma unroll
    for (int ct = 0; ct < 4; ct++) {
#pragma unroll
      for (int tt = 0; tt < 2; tt++) {
        acc[tt][ct] = __builtin_amdgcn_mfma_f32_16x16x32_bf16(pf[tt][0], vf[ct][0], acc[tt][ct], 0, 0, 0);
        acc[tt][ct] = __builtin_amdgcn_mfma_f32_16x16x32_bf16(pf[tt][1], vf[ct][1], acc[tt][ct], 0, 0, 0);
      }
    }
#pragma unroll
    for (int tt = 0; tt < 2; tt++) {
      acc[tt][4] = __builtin_amdgcn_mfma_f32_16x16x32_bf16(pf[tt][0], onesf, acc[tt][4], 0, 0, 0);
      acc[tt][4] = __builtin_amdgcn_mfma_f32_16x16x32_bf16(pf[tt][1], onesf, acc[tt][4], 0, 0, 0);
    }
  }
  // --- epilogue per tile: /l, transpose via pl, coalesced stores to o_t ---
  int n = nh >> 2, h = nh & 3;
#pragma unroll
  for (int tt = 0; tt < 2; tt++) {
    float linv[4];
#pragma unroll
    for (int r = 0; r < 4; r++)
      linv[r] = 1.0f / __shfl(acc[tt][4][r], lane & 48);  // col-0 lane of quad
    asm volatile("" ::: "memory");
#pragma unroll
    for (int t = 0; t < 4; t++) {
      int us_[4];
#pragma unroll
      for (int r = 0; r < 4; r++) us_[r] = f2bf_bits(acc[tt][t][r] * linv[r]);
      int xv0 = dppx1i(us_[0]);
      int xv1 = dppx1i(us_[1]);
      int xv2 = dppx1i(us_[2]);
      int xv3 = dppx1i(us_[3]);
      if (ev) {
        *(int*)(pl + (quad * 4 + 0) * 66 + t * 16 + c) = (xv0 << 16) | us_[0];
        *(int*)(pl + (quad * 4 + 1) * 66 + t * 16 + c) = (xv1 << 16) | us_[1];
      } else {
        *(int*)(pl + (quad * 4 + 2) * 66 + t * 16 + (c - 1)) = (us_[2] << 16) | xv2;
        *(int*)(pl + (quad * 4 + 3) * 66 + t * 16 + (c - 1)) = (us_[3] << 16) | xv3;
      }
    }
    asm volatile("" ::: "memory");
    int row = lane >> 2, seg = lane & 3;
    short8 o0 = *(const short8*)(pl + row * 66 + seg * 16);
    short8 o1 = *(const short8*)(pl + row * 66 + seg * 16 + 8);
    short* dst = (short*)ot + ((size_t)n * 1600 + l0 + tt * 16 + row) * 256 + h * 64 + seg * 16;
    *(short8*)(dst) = o0;
    *(short8*)(dst + 8) = o1;
    asm volatile("" ::: "memory");  // pl reused by next tile
  }
}

// ---------------------------------------------------------------------------
// K3: (1,9) conv as MFMA GEMM (unchanged from round 9).
// ---------------------------------------------------------------------------
__global__ void k_conv9(const bf16* __restrict__ ot, const bf16* __restrict__ Wt,
                        const float* __restrict__ bo, const float* __restrict__ g1,
                        const float* __restrict__ be1, const float* __restrict__ mu1,
                        const float* __restrict__ va1, const float* __restrict__ x,
                        bf16* __restrict__ y, bf16* __restrict__ yt) {
  __shared__ short tl[2][16 * 66];
  int wv = threadIdx.x >> 6;
  int lane = threadIdx.x & 63;
  int quad = lane >> 4, c = lane & 15;
  int n = blockIdx.y;
  int l0 = blockIdx.x * 32 + wv * 16;
  int la = l0 + c;
  int va = la % 25;
  const short* obase = (const short*)ot + (size_t)n * 409600;
  const short* wbase = (const short*)Wt;
  f32x4 acc[4] = {};
  for (int r = 0; r < 9; r++) {
    int sh = r - 4;
    bool valid = (unsigned)(va + sh) < 25u;
    int lp = la + sh;
    lp = max(0, min(1599, lp));
    const short* arow = obase + (size_t)lp * 256 + quad * 8;
    const short* wrow = wbase + (size_t)r * 8 * 4 * 64 * 8 + lane * 8;
    short8 z8 = {0, 0, 0, 0, 0, 0, 0, 0};
#pragma unroll 4
    for (int kc = 0; kc < 8; kc++) {
      short8 af = *(const short8*)(arow + kc * 32);
      af = valid ? af : z8;
      const short* wk = wrow + kc * 4 * 64 * 8;
      short8 b0 = *(const short8*)(wk);
      short8 b1 = *(const short8*)(wk + 512);
      short8 b2 = *(const short8*)(wk + 1024);
      short8 b3 = *(const short8*)(wk + 1536);
      acc[0] = __builtin_amdgcn_mfma_f32_16x16x32_bf16(af, b0, acc[0], 0, 0, 0);
      acc[1] = __builtin_amdgcn_mfma_f32_16x16x32_bf16(af, b1, acc[1], 0, 0, 0);
      acc[2] = __builtin_amdgcn_mfma_f32_16x16x32_bf16(af, b2, acc[2], 0, 0, 0);
      acc[3] = __builtin_amdgcn_mfma_f32_16x16x32_bf16(af, b3, acc[3], 0, 0, 0);
    }
  }
  short* tlw = &tl[wv][0];
  float outv[4][4];
#pragma unroll
  for (int cot = 0; cot < 4; cot++) {
    int co = cot * 16 + c;
    float inv = g1[co] * rsqrtf(va1[co] + 1e-5f);
    float add = be1[co] - mu1[co] * inv + bo[co] * inv;
    f32x4 xr = *(const f32x4*)(x + (size_t)(n * 64 + co) * 1600 + l0 + quad * 4);
    us4 yb;
#pragma unroll
    for (int rr = 0; rr < 4; rr++) {
      float vv = fmaxf(acc[cot][rr] * inv + add + xr[rr], 0.f);
      outv[cot][rr] = vv;
      yb[rr] = f2bf_bits(vv);
    }
    *(us4*)((short*)y + (size_t)(n * 64 + co) * 1600 + l0 + quad * 4) = yb;
  }
  asm volatile("" ::: "memory");
  bool ev = (c & 1) == 0;
#pragma unroll
  for (int cot = 0; cot < 4; cot++) {
    int us_[4];
#pragma unroll
    for (int rr = 0; rr < 4; rr++) us_[rr] = f2bf_bits(outv[cot][rr]);
    int xv0 = dppx1i(us_[0]);
    int xv1 = dppx1i(us_[1]);
    int xv2 = dppx1i(us_[2]);
    int xv3 = dppx1i(us_[3]);
    if (ev) {
      *(int*)(tlw + (quad * 4 + 0) * 66 + cot * 16 + c) = (xv0 << 16) | us_[0];
      *(int*)(tlw + (quad * 4 + 1) * 66 + cot * 16 + c) = (xv1 << 16) | us_[1];
    } else {
      *(int*)(tlw + (quad * 4 + 2) * 66 + cot * 16 + (c - 1)) = (us_[2] << 16) | xv2;
      *(int*)(tlw + (quad * 4 + 3) * 66 + cot * 16 + (c - 1)) = (us_[3] << 16) | xv3;
    }
  }
  asm volatile("" ::: "memory");
  int row = lane >> 2, seg = lane & 3;
  short8 y0 = *(const short8*)(tlw + row * 66 + seg * 16);
  short8 y1 = *(const short8*)(tlw + row * 66 + seg * 16 + 8);
  short* yd = (short*)yt + ((size_t)n * 1600 + l0 + row) * 64 + seg * 16;
  *(short8*)(yd) = y0;
  *(short8*)(yd + 8) = y1;
}

// ---------------------------------------------------------------------------
// K4: 1x1 conv as MFMA GEMM (unchanged).
// ---------------------------------------------------------------------------
__global__ void k_ff(const bf16* __restrict__ yt, const bf16* __restrict__ WfT,
                     const bf16* __restrict__ y, const float* __restrict__ bff,
                     const float* __restrict__ g2, const float* __restrict__ be2,
                     const float* __restrict__ mu2, const float* __restrict__ va2,
                     float* __restrict__ out) {
  int wv = threadIdx.x >> 6;
  int lane = threadIdx.x & 63;
  int quad = lane >> 4, c = lane & 15;
  int n = blockIdx.y;
  int l0 = blockIdx.x * 32 + wv * 16;
  const short* arow = (const short*)yt + ((size_t)n * 1600 + l0 + c) * 64 + quad * 8;
  const short* wbase = (const short*)WfT + lane * 8;
  f32x4 acc[4] = {};
#pragma unroll
  for (int kc = 0; kc < 2; kc++) {
    short8 af = *(const short8*)(arow + kc * 32);
    const short* wk = wbase + kc * 2048;
    short8 b0 = *(const short8*)(wk);
    short8 b1 = *(const short8*)(wk + 512);
    short8 b2 = *(const short8*)(wk + 1024);
    short8 b3 = *(const short8*)(wk + 1536);
    acc[0] = __builtin_amdgcn_mfma_f32_16x16x32_bf16(af, b0, acc[0], 0, 0, 0);
    acc[1] = __builtin_amdgcn_mfma_f32_16x16x32_bf16(af, b1, acc[1], 0, 0, 0);
    acc[2] = __builtin_amdgcn_mfma_f32_16x16x32_bf16(af, b2, acc[2], 0, 0, 0);
    acc[3] = __builtin_amdgcn_mfma_f32_16x16x32_bf16(af, b3, acc[3], 0, 0, 0);
  }
#pragma unroll
  for (int cot = 0; cot < 4; cot++) {
    int co = cot * 16 + c;
    float inv = g2[co] * rsqrtf(va2[co] + 1e-5f);
    float add = be2[co] - mu2[co] * inv + bff[co] * inv;
    size_t base = (size_t)(n * 64 + co) * 1600 + l0 + quad * 4;
    us4 yr = *(const us4*)((const short*)y + base);
    f32x4 ov;
#pragma unroll
    for (int rr = 0; rr < 4; rr++) {
      unsigned short ub = yr[rr];
      float yv;
      *(unsigned*)&yv = ((unsigned)ub) << 16;  // bf16 bits -> f32
      ov[rr] = fmaxf(acc[cot][rr] * inv + add + yv, 0.f);
    }
    *(f32x4*)(out + base) = ov;
  }
}

extern "C" void kernel_launch(void* const* d_in, const int* in_sizes, int n_in,
                              void* d_out, int out_size, void* d_ws, size_t ws_size,
                              hipStream_t stream) {
  const float* x   = (const float*)d_in[0];
  const float* Wq  = (const float*)d_in[1];
  const float* bq  = (const float*)d_in[2];
  const float* Wo  = (const float*)d_in[3];
  const float* bo  = (const float*)d_in[4];
  const float* g1  = (const float*)d_in[5];
  const float* be1 = (const float*)d_in[6];
  const float* mu1 = (const float*)d_in[7];
  const float* va1 = (const float*)d_in[8];
  const float* Wf  = (const float*)d_in[9];
  const float* bff = (const float*)d_in[10];
  const float* g2  = (const float*)d_in[11];
  const float* be2 = (const float*)d_in[12];
  const float* mu2 = (const float*)d_in[13];
  const float* va2 = (const float*)d_in[14];

  // ws (bf16 elems): q,k [nh][l][64]; vt [nh][64][l]; ot [n][l][256];
  //                  y [n][64][l]; yt [n][l][64]; Wt; WfT; WqT   (~46.6MB)
  const size_t QKV = (size_t)64 * 1600 * 64;
  bf16* qw  = (bf16*)d_ws;
  bf16* kw  = qw + QKV;
  bf16* vtw = kw + QKV;
  bf16* otw = vtw + QKV;
  bf16* yw  = otw + QKV;
  bf16* ytw = yw + 1638400;
  bf16* Wt  = ytw + 1638400;
  bf16* WfT = Wt + 147456;
  bf16* WqT = WfT + 4096;

  k_prep<<<576, 256, 0, stream>>>(Wo, Wf, Wq, Wt, WfT, WqT);
  k_qkv<<<1600, 64, 0, stream>>>(x, WqT, bq, qw, kw, vtw);
  k_attn<<<1600, 128, 0, stream>>>(qw, kw, vtw, otw);
  dim3 gc(50, 16);
  k_conv9<<<gc, 128, 0, stream>>>(otw, Wt, bo, g1, be1, mu1, va1, x, yw, ytw);
  k_ff<<<gc, 128, 0, stream>>>(ytw, WfT, yw, bff, g2, be2, mu2, va2, (float*)d_out);
}